// Round 10
// baseline (505.137 us; speedup 1.0000x reference)
//
#include <hip/hip_runtime.h>

#define N 8192
#define K1 31              // K=30 -> k+1 = 31 kept per row/column
#define CAP 256            // candidate capacity per line (lambda ~88, P(>256)~1e-48)
#define WCAP 256           // per-wave LDS candidate buffer (~22 expected hits/wave)
#define CSTRIDE 16         // colcnt padded: one u32 counter per 64B line
// Fixed threshold: input is i.i.d. N(0,1) (jax.random.normal). t=2.3f
// (bits 0x40133333): lambda = 8192*P(X>2.3) ~= 88 candidates/line.
// P(line < 31) ~ 1e-12 -> fallback (exact for ANY input) fires ~never.
#define GBITS 0x40133333u

typedef unsigned int u32;
typedef unsigned long long u64;
typedef u32 u32x4 __attribute__((ext_vector_type(4)));   // native vector for NT builtins

// monotone fp32-bits -> u32 key (larger float => larger key)
__device__ __forceinline__ u32 fkey(u32 u) {
    return (u & 0x80000000u) ? ~u : (u | 0x80000000u);
}
// inverse of fkey (exact bit recovery of the original float)
__device__ __forceinline__ u32 fkey_inv(u32 k) {
    return (k & 0x80000000u) ? (k ^ 0x80000000u) : ~k;
}
// pack (key, idx): larger u64 = larger key, or equal key and SMALLER idx
__device__ __forceinline__ u64 pack_ki(u32 key, u32 idx) {
    return ((u64)key << 32) | (u32)(~idx);
}

// ============================================================================
// 0a) zero the 256 MB output with NT wide stores (replaces hipMemsetAsync —
//     avoids any graph-capture risk from runtime memset nodes; same BW class
//     as the runtime fill kernel, ~6.4 TB/s measured for this pattern).
// ============================================================================
__global__ __launch_bounds__(256) void zero_out_kernel(u32x4* __restrict__ o4) {
    const u32x4 z = (u32x4)(0u);
    const size_t total = (size_t)N * N / 4;              // 16M uint4
    size_t i = (size_t)blockIdx.x * 256 + threadIdx.x;
    const size_t gs = (size_t)gridDim.x * 256;
    for (; i < total; i += gs) __builtin_nontemporal_store(z, &o4[i]);
}

// ============================================================================
// 0b) zero: padded col counters, row counters, pre-flags
// ============================================================================
__global__ __launch_bounds__(256) void init_kernel(u32* __restrict__ colcnt_pad,
                                                   u32* __restrict__ rowcnt,
                                                   u32* __restrict__ preflg) {
    const int i = blockIdx.x * 256 + threadIdx.x;
    const int gs = (int)gridDim.x * 256;
    for (int j = i; j < N * CSTRIDE; j += gs) colcnt_pad[j] = 0u;
    for (int j = i; j < N; j += gs) rowcnt[j] = 0u;
    for (int j = i; j < 2 * N; j += gs) preflg[j] = 0u;
}

// ============================================================================
// 1) barrier-free streaming extraction. One block per row, each wave owns a
//    contiguous quarter: private LDS buffer + LDS counter. Nontemporal load
//    of A (single-use stream, keep L2 for candidate structures). Flush: one
//    device atomicAdd per wave reserves a packed rowcand segment; col entries
//    emitted per hit. Overflow (wave>WCAP) pre-flags the row and emits the
//    col entry inline -> counts stay exact.
// ============================================================================
__global__ __launch_bounds__(256) void extract_kernel(
        const float* __restrict__ A,
        u64* __restrict__ rowcand, u64* __restrict__ colcand,
        u32* __restrict__ rowcnt, u32* __restrict__ colcnt_pad,
        u32* __restrict__ preflg) {
    __shared__ u64 buf[4][WCAP];
    __shared__ u32 wc[4];
    const int tid  = threadIdx.x;
    const int lane = tid & 63;
    const int w    = tid >> 6;
    const int row  = blockIdx.x;
    if (tid < 4) wc[tid] = 0u;
    __syncthreads();                                  // once, before any loads
    const u32 g = fkey(GBITS);
    const u32x4* A4 = (const u32x4*)(A + (size_t)row * N);
    u32x4 v[8];
#pragma unroll
    for (int it = 0; it < 8; ++it)
        v[it] = __builtin_nontemporal_load(&A4[w * 512 + it * 64 + lane]);  // 8 in flight
#pragma unroll
    for (int it = 0; it < 8; ++it) {
        const int j = (w * 512 + it * 64 + lane) * 4;
        u32 ks[4] = { fkey(v[it].x), fkey(v[it].y), fkey(v[it].z), fkey(v[it].w) };
#pragma unroll
        for (int q = 0; q < 4; ++q) {
            if (ks[q] >= g) {
                u32 slot = atomicAdd(&wc[w], 1u);     // wave-private LDS counter
                if (slot < WCAP) {
                    buf[w][slot] = pack_ki(ks[q], (u32)(j + q));
                } else {
                    // wave buffer overflow (~impossible): flag row, emit col inline
                    atomicOr(&preflg[row], 1u);
                    const int c = j + q;
                    u32 cs = atomicAdd(&colcnt_pad[(size_t)c * CSTRIDE], 1u);
                    if (cs < CAP) colcand[(size_t)c * CAP + cs] = pack_ki(ks[q], (u32)row);
                }
            }
        }
    }
    // per-wave flush (no block barrier): reserve packed segment, emit entries
    const u32 cw = wc[w];                             // same-wave DS ordering
    const u32 stored = cw < (u32)WCAP ? cw : (u32)WCAP;
    u32 base = 0u;
    if (lane == 0) base = atomicAdd(&rowcnt[row], cw);  // exact total for flags
    base = __shfl(base, 0);
    for (u32 i = lane; i < stored; i += 64) {
        const u64 e = buf[w][i];
        const u32 key = (u32)(e >> 32);
        const u32 c   = ~(u32)e;
        if (base + i < (u32)CAP) rowcand[(size_t)row * CAP + base + i] = e;
        u32 cs = atomicAdd(&colcnt_pad[(size_t)c * CSTRIDE], 1u);
        if (cs < CAP) colcand[(size_t)c * CAP + cs] = pack_ki(key, (u32)row);
    }
}

// ============================================================================
// 2) merged exact select (2N blocks: b<N rows, else cols): 31st-largest
//    (key,idx) via pairwise rank over the candidate list. Flags lines
//    needing the fallback (preflagged, cnt<31, or cnt>CAP).
// ============================================================================
__global__ __launch_bounds__(256) void rank_select_kernel(
        const u64* __restrict__ rowcand, const u64* __restrict__ colcand,
        const u32* __restrict__ rowcnt, const u32* __restrict__ colcnt_pad,
        const u32* __restrict__ preflg,
        u32* __restrict__ tk, int* __restrict__ L, u32* __restrict__ flag) {
    __shared__ u64 buf[CAP];
    const int b   = blockIdx.x;
    const int tid = threadIdx.x;
    const bool isrow = b < N;
    const u64* cand = isrow ? rowcand + (size_t)b * CAP
                            : colcand + (size_t)(b - N) * CAP;
    const u32 cnt = isrow ? rowcnt[b] : colcnt_pad[(size_t)(b - N) * CSTRIDE];
    if (preflg[b] != 0u || cnt < (u32)K1 || cnt > (u32)CAP) {
        if (tid == 0) flag[b] = 1u;
        return;
    }
    if (tid == 0) flag[b] = 0u;
    if (tid < (int)cnt) buf[tid] = cand[tid];        // cnt <= CAP = 256
    __syncthreads();
    if (tid < (int)cnt) {
        const u64 mine = buf[tid];
        u32 r = 0;
        for (u32 q = 0; q < cnt; ++q) r += (buf[q] > mine) ? 1u : 0u;  // LDS broadcast
        if (r == (u32)(K1 - 1)) {
            tk[b] = (u32)(mine >> 32);
            L[b]  = (int)(~(u32)mine);
        }
    }
}

// ============================================================================
// 3) merged exact fallback (2N blocks, rare: early-exits on clear flag).
//    Full LDS radix-256 select over 32-bit keys + binary-searched tie
//    index L. b<N: row b (stride 1); else: column b-N (stride N).
// ============================================================================
__global__ __launch_bounds__(256) void fallback_select_kernel(
        const float* __restrict__ A, const u32* __restrict__ flag,
        u32* __restrict__ tk, int* __restrict__ L_out) {
    if (flag[blockIdx.x] == 0u) return;
    __shared__ u32 keys[N];            // 32 KB
    __shared__ u32 hist[4][256];
    __shared__ u32 scanb[256];
    __shared__ u32 sh_sel, sh_want, sh_gt, sh_cnt;

    const int b    = blockIdx.x;
    const int tid  = threadIdx.x;
    const int wave = tid >> 6;
    const bool isrow = b < N;
    const size_t base    = isrow ? (size_t)b * N : (size_t)(b - N);
    const size_t estride = isrow ? 1 : (size_t)N;

    for (int it = 0; it < N / 256; ++it) {
        int j = it * 256 + tid;
        keys[j] = fkey(__float_as_uint(A[base + (size_t)j * estride]));
    }
    if (tid == 0) { sh_sel = 0u; sh_want = (u32)K1; sh_gt = 0u; }
    __syncthreads();

    for (int pass = 3; pass >= 0; --pass) {
        const u32 pref = sh_sel;
        const u32 want = sh_want;
        hist[0][tid] = 0u; hist[1][tid] = 0u; hist[2][tid] = 0u; hist[3][tid] = 0u;
        __syncthreads();
        const u32 pmask = (pass == 3) ? 0u : (0xFFFFFFFFu << ((pass + 1) * 8));
        const int shift = pass * 8;
        for (int it = 0; it < N / 256; ++it) {
            u32 k = keys[it * 256 + tid];
            if ((k & pmask) == (pref & pmask))
                atomicAdd(&hist[wave][(k >> shift) & 0xFFu], 1u);
        }
        __syncthreads();
        scanb[tid] = hist[0][tid] + hist[1][tid] + hist[2][tid] + hist[3][tid];
        __syncthreads();
        for (int off = 1; off < 256; off <<= 1) {
            u32 add = (tid + off < 256) ? scanb[tid + off] : 0u;
            __syncthreads();
            scanb[tid] += add;
            __syncthreads();
        }
        u32 incl = scanb[tid];
        u32 abov = (tid < 255) ? scanb[tid + 1] : 0u;
        if (incl >= want && abov < want) {
            sh_sel  = pref | ((u32)tid << shift);
            sh_want = want - abov;
        }
        __syncthreads();
    }
    const u32 tkey = sh_sel;

    u32 my = 0;
    for (int it = 0; it < N / 256; ++it) my += (keys[it * 256 + tid] > tkey) ? 1u : 0u;
    atomicAdd(&sh_gt, my);
    __syncthreads();
    const int m = K1 - (int)sh_gt;     // ties to accept, >= 1

    // binary search smallest X with #(ties at idx<=X) >= m  -> L = X
    int lo = 0, hi = N - 1;
    while (lo < hi) {
        int mid = (lo + hi) >> 1;
        if (tid == 0) sh_cnt = 0u;
        __syncthreads();
        u32 c = 0;
        for (int it = 0; it < N / 256; ++it) {
            int j = it * 256 + tid;
            c += (keys[j] == tkey && j <= mid) ? 1u : 0u;
        }
        atomicAdd(&sh_cnt, c);
        __syncthreads();
        if ((int)sh_cnt >= m) hi = mid; else lo = mid + 1;
        __syncthreads();               // protect sh_cnt reuse
    }
    if (tid == 0) { tk[b] = tkey; L_out[b] = lo; }
}

// ============================================================================
// 4) scatter: out was zeroed by zero_out_kernel. For each row, re-check its
//    candidates against row AND col thresholds and write the <=31 survivors.
//    Correctness: unflagged rows have tk_row >= g and a complete, packed
//    rowcand -> every survivor is present. Flagged rows re-scan A.
// ============================================================================
__global__ __launch_bounds__(256) void scatter_kernel(
        const float* __restrict__ A,
        const u64* __restrict__ rowcand, const u32* __restrict__ rowcnt,
        const u32* __restrict__ flag,
        const u32* __restrict__ tk, const int* __restrict__ L,
        float* __restrict__ out) {
    const int i   = blockIdx.x;
    const int tid = threadIdx.x;
    const u32 tr = tk[i];
    const int lr = L[i];
    if (flag[i] == 0u) {
        const u32 cnt = rowcnt[i];               // <= CAP (else flagged)
        if (tid < (int)cnt) {
            const u64 e = rowcand[(size_t)i * CAP + tid];
            const u32 k = (u32)(e >> 32);
            const int j = (int)(~(u32)e);
            bool rok = (k > tr) || (k == tr && j <= lr);
            if (rok) {
                const u32 tcv = tk[N + j];
                const int lcv = L[N + j];
                bool cok = (k > tcv) || (k == tcv && i <= lcv);
                if (cok && i != j)
                    out[(size_t)i * N + j] = __uint_as_float(fkey_inv(k));
            }
        }
    } else {
        // rare: full row re-scan (thresholds may be below g)
        const uint4* A4 = (const uint4*)(A + (size_t)i * N);
        for (int it = 0; it < 8; ++it) {
            uint4 v = A4[it * 256 + tid];
            const int j0 = (it * 256 + tid) * 4;
            u32 bs[4] = { v.x, v.y, v.z, v.w };
#pragma unroll
            for (int q = 0; q < 4; ++q) {
                const int j = j0 + q;
                const u32 k = fkey(bs[q]);
                bool rok = (k > tr) || (k == tr && j <= lr);
                if (!rok) continue;
                const u32 tcv = tk[N + j];
                const int lcv = L[N + j];
                bool cok = (k > tcv) || (k == tcv && i <= lcv);
                if (cok && i != j)
                    out[(size_t)i * N + j] = __uint_as_float(bs[q]);
            }
        }
    }
}

// ============================================================================
extern "C" void kernel_launch(void* const* d_in, const int* in_sizes, int n_in,
                              void* d_out, int out_size, void* d_ws, size_t ws_size,
                              hipStream_t stream) {
    const float* A   = (const float*)d_in[0];
    float*       out = (float*)d_out;

    // ---- everything lives in ws (~33 MB of the 1 GiB workspace) ----
    u64* rowcand    = (u64*)d_ws;                                // 16 MB
    u64* colcand    = rowcand + (size_t)N * CAP;                 // 16 MB
    u32* colcnt_pad = (u32*)(colcand + (size_t)N * CAP);         // 512 KB
    u32* rowcnt     = colcnt_pad + (size_t)N * CSTRIDE;          // N
    u32* preflg     = rowcnt + N;                                // 2N
    u32* flag       = preflg + 2 * N;                            // 2N
    u32* tk         = flag + 2 * N;                              // 2N
    int* L          = (int*)(tk + 2 * N);                        // 2N

    zero_out_kernel<<<dim3(2048), dim3(256), 0, stream>>>((u32x4*)d_out);
    init_kernel<<<dim3(128), dim3(256), 0, stream>>>(colcnt_pad, rowcnt, preflg);
    extract_kernel<<<dim3(N), dim3(256), 0, stream>>>(A, rowcand, colcand,
                                                      rowcnt, colcnt_pad, preflg);
    rank_select_kernel<<<dim3(2 * N), dim3(256), 0, stream>>>(rowcand, colcand, rowcnt,
                                                              colcnt_pad, preflg, tk, L, flag);
    fallback_select_kernel<<<dim3(2 * N), dim3(256), 0, stream>>>(A, flag, tk, L);
    scatter_kernel<<<dim3(N), dim3(256), 0, stream>>>(A, rowcand, rowcnt, flag, tk, L, out);
}